// Round 7
// baseline (572.455 us; speedup 1.0000x reference)
//
#include <hip/hip_runtime.h>
#include <hip/hip_bf16.h>
#include <math.h>

#define S 4096
#define HQ 8
#define NKVH 4
#define D 256
#define HID 2304
#define SW 2048
#define QDIM 2048
#define KVDIM 1024
#define QKVDIM 4096          // fused Q(2048) | K(1024) | V(1024)
#define SCALE 0.0625f
#define SOFTCAP 50.0f

typedef __attribute__((ext_vector_type(4))) float f32x4;
typedef __attribute__((ext_vector_type(8))) short short8;   // 8 bf16 = 4 VGPRs (MFMA A/B frag)

__device__ __forceinline__ float bf2f(unsigned v) { return __uint_as_float(v << 16); }
__device__ __forceinline__ unsigned f2bf(float f) {
    unsigned u = __float_as_uint(f);
    return (u + 0x7fffu + ((u >> 16) & 1u)) >> 16;   // round-to-nearest-even
}

__device__ __forceinline__ void store_c(float* p, float v) { *p = v; }
__device__ __forceinline__ void store_c(unsigned short* p, float v) { *p = (unsigned short)f2bf(v); }

// async global->LDS, 16B per lane; lds dst is wave-uniform base (HW adds lane*16)
__device__ __forceinline__ void glls16(const void* g, void* l) {
    __builtin_amdgcn_global_load_lds(
        (const __attribute__((address_space(1))) unsigned int*)g,
        (__attribute__((address_space(3))) unsigned int*)l, 16, 0, 0);
}

// ---------------------------------------------------------------------------
// fp32 -> bf16 elementwise (float4 per thread)
// ---------------------------------------------------------------------------
__global__ __launch_bounds__(256) void cvt_bf16(const float* __restrict__ in,
                                                unsigned short* __restrict__ out)
{
    int i = blockIdx.x * 256 + threadIdx.x;
    float4 v = ((const float4*)in)[i];
    uint2 o;
    o.x = f2bf(v.x) | (f2bf(v.y) << 16);
    o.y = f2bf(v.z) | (f2bf(v.w) << 16);
    ((uint2*)out)[i] = o;
}

// ---------------------------------------------------------------------------
// 128x128-tile GEMM (verified m97-style structure) — kept for O-projection.
// C[M][N] = A[M][K] @ B[N][K]^T, bf16 in, fp32 accumulate, TC out.
// ---------------------------------------------------------------------------
template <typename TC>
__global__ __launch_bounds__(256) void bf16_gemm_bt(const unsigned short* __restrict__ A,
                                                    const unsigned short* __restrict__ B,
                                                    TC* __restrict__ C,
                                                    int M, int N, int K)
{
    __shared__ unsigned short As[2][16 * 512];   // 16 frags x 1 KiB per buffer
    __shared__ unsigned short Bs[2][16 * 512];
    const int t = threadIdx.x;

    // bijective XCD swizzle of the flattened tile id
    const int nbx = gridDim.x;
    const int nwg = nbx * gridDim.y;
    int flat = blockIdx.y * nbx + blockIdx.x;
    const int q8 = nwg >> 3, r8 = nwg & 7;
    const int xcd = flat & 7, orig = flat >> 3;
    const int wg = (xcd < r8 ? xcd * (q8 + 1) : r8 * (q8 + 1) + (xcd - r8) * q8) + orig;
    // grouped raster: bands of 8 m-tiles, n sweeps within a band
    const int band = wg / (8 * nbx);
    const int rem  = wg - band * 8 * nbx;
    const int m0 = (band * 8 + (rem & 7)) * 128;
    const int n0 = (rem >> 3) * 128;

    const int w = t >> 6, lid = t & 63, n16 = lid & 15, quad = lid >> 4;
    const int wm = (w >> 1) * 64, wn = (w & 1) * 64;

    f32x4 acc[4][4] = {};

    auto stage = [&](int buf, int k0) {
        #pragma unroll
        for (int it = 0; it < 4; ++it) {
            int f  = it * 4 + w;              // wave-uniform frag id 0..15
            int fm = f >> 1, fk = f & 1;
            const size_t goff = (size_t)(fm * 16 + n16) * K + k0 + fk * 32 + quad * 8;
            glls16(A + (size_t)m0 * K + goff, &As[buf][f * 512]);
            glls16(B + (size_t)n0 * K + goff, &Bs[buf][f * 512]);
        }
    };

    const int nk = K / 64;
    stage(0, 0);
    int cur = 0;
    for (int kk = 0; kk < nk; ++kk) {
        asm volatile("s_waitcnt vmcnt(0)" ::: "memory");   // own staging done
        __syncthreads();                                   // everyone's visible
        if (kk + 1 < nk) stage(cur ^ 1, (kk + 1) * 64);    // prefetch next panel
        #pragma unroll
        for (int ks = 0; ks < 2; ++ks) {
            short8 af[4], bfr[4];
            #pragma unroll
            for (int x = 0; x < 4; ++x) {
                af[x]  = *(const short8*)(&As[cur][(((wm >> 4) + x) * 2 + ks) * 512 + lid * 8]);
                bfr[x] = *(const short8*)(&Bs[cur][(((wn >> 4) + x) * 2 + ks) * 512 + lid * 8]);
            }
            __builtin_amdgcn_s_setprio(1);
            #pragma unroll
            for (int i = 0; i < 4; ++i)
                #pragma unroll
                for (int j = 0; j < 4; ++j)
                    acc[i][j] = __builtin_amdgcn_mfma_f32_16x16x32_bf16(af[i], bfr[j], acc[i][j], 0, 0, 0);
            __builtin_amdgcn_s_setprio(0);
        }
        cur ^= 1;
    }

    #pragma unroll
    for (int i = 0; i < 4; ++i) {
        #pragma unroll
        for (int j = 0; j < 4; ++j) {
            int rbase = m0 + wm + i * 16 + quad * 4;
            int col   = n0 + wn + j * 16 + n16;
            #pragma unroll
            for (int rg = 0; rg < 4; ++rg)
                store_c(C + (size_t)(rbase + rg) * N + col, acc[i][j][rg]);
        }
    }
}

// ---------------------------------------------------------------------------
// 256x256-tile 8-phase GEMM (T3+T4: counted vmcnt), bf16->bf16. 512 threads =
// 8 waves (2m x 4n), per-wave output 128x64, BK=64, 2 K-tiles/iteration.
// Fragment-major LDS => conflict-free without byte-swizzle. LDS = 128 KiB.
// Staging schedule + per-phase vmcnt ledger as verified in R6 (passing).
// ---------------------------------------------------------------------------
__global__ __launch_bounds__(512, 2) void bf16_gemm_8ph(const unsigned short* __restrict__ A,
                                                        const unsigned short* __restrict__ B,
                                                        unsigned short* __restrict__ C,
                                                        int M, int N, int K)
{
    __shared__ unsigned short As[2][32 * 512];   // 32 frags (16 m x 2 ks) x 1 KiB
    __shared__ unsigned short Bs[2][32 * 512];   // 32 frags (16 n x 2 ks) x 1 KiB
    const int t = threadIdx.x;
    const int w = t >> 6, lid = t & 63, n16 = lid & 15, quad = lid >> 4;

    // XCD chunk swizzle (grid = 256, 32 blocks/XCD contiguous)
    const int flat = blockIdx.x;
    const int wg = (flat & 7) * 32 + (flat >> 3);
    const int m0 = (wg >> 4) * 256, n0 = (wg & 15) * 256;

    const int wmf = (w >> 2) * 8;             // wave m-frag base (0 or 8)
    const int wnf = (w & 3) * 4;              // wave n-frag base (0,4,8,12)
    const int fnw = (w >> 1) * 4 + (w & 1);   // B nh0 staging frag for this wave

    f32x4 acc[8][4] = {};

    auto stageA = [&](int buf, int k0, int fm) {
        glls16(A + (size_t)(m0 + fm * 16 + n16) * K + k0 + quad * 8,
               &As[buf][(fm * 2 + 0) * 512]);
        glls16(A + (size_t)(m0 + fm * 16 + n16) * K + k0 + 32 + quad * 8,
               &As[buf][(fm * 2 + 1) * 512]);
    };
    auto stageB = [&](int buf, int k0, int fn) {
        glls16(B + (size_t)(n0 + fn * 16 + n16) * K + k0 + quad * 8,
               &Bs[buf][(fn * 2 + 0) * 512]);
        glls16(B + (size_t)(n0 + fn * 16 + n16) * K + k0 + 32 + quad * 8,
               &Bs[buf][(fn * 2 + 1) * 512]);
    };
    // bijective wave->frag assignments matching the read sets:
    auto sAm0 = [&](int buf, int k0){ stageA(buf, k0, (w & 3) + (w >> 2) * 8); };      // {0..3, 8..11}
    auto sAm1 = [&](int buf, int k0){ stageA(buf, k0, 4 + (w & 3) + (w >> 2) * 8); };  // {4..7, 12..15}
    auto sBn0 = [&](int buf, int k0){ stageB(buf, k0, fnw); };                          // {0,1,4,5,8,9,12,13}
    auto sBn1 = [&](int buf, int k0){ stageB(buf, k0, fnw + 2); };                      // {2,3,6,7,10,11,14,15}

#define GPHASE(mh, nh, buf, STAGE, WAITSTR)                                          \
    {                                                                                \
        short8 afr[4][2], bfr[2][2];                                                 \
        _Pragma("unroll") for (int i = 0; i < 4; ++i)                                \
            _Pragma("unroll") for (int ks = 0; ks < 2; ++ks)                         \
                afr[i][ks] = *(const short8*)(&As[buf][((wmf + (mh)*4 + i)*2 + ks)*512 + lid*8]); \
        _Pragma("unroll") for (int j = 0; j < 2; ++j)                                \
            _Pragma("unroll") for (int ks = 0; ks < 2; ++ks)                         \
                bfr[j][ks] = *(const short8*)(&Bs[buf][((wnf + (nh)*2 + j)*2 + ks)*512 + lid*8]); \
        STAGE;                                                                       \
        __builtin_amdgcn_s_barrier();                                                \
        asm volatile("s_waitcnt lgkmcnt(0)" ::: "memory");                           \
        __builtin_amdgcn_sched_barrier(0);                                           \
        __builtin_amdgcn_s_setprio(1);                                               \
        _Pragma("unroll") for (int i = 0; i < 4; ++i)                                \
            _Pragma("unroll") for (int j = 0; j < 2; ++j)                            \
                _Pragma("unroll") for (int ks = 0; ks < 2; ++ks)                     \
                    acc[(mh)*4 + i][(nh)*2 + j] = __builtin_amdgcn_mfma_f32_16x16x32_bf16( \
                        afr[i][ks], bfr[j][ks], acc[(mh)*4 + i][(nh)*2 + j], 0, 0, 0); \
        __builtin_amdgcn_s_setprio(0);                                               \
        asm volatile(WAITSTR ::: "memory");                                          \
        __builtin_amdgcn_s_barrier();                                                \
    }

    const int nk = K / 64;            // 2304/64 = 36
    const int niter = nk / 2;         // 18

    // prologue: all of b0 (tile 0), then b1.A-mh0 + b1.B-nh0 (tile 1)
    sAm0(0, 0); sBn0(0, 0); sAm1(0, 0); sBn1(0, 0);
    sAm0(1, 64); sBn0(1, 64);
    asm volatile("s_waitcnt vmcnt(4)" ::: "memory");   // first 8 glls (= all b0) done
    __builtin_amdgcn_s_barrier();

    for (int I = 0; I < niter - 1; ++I) {
        const int kc = I * 128;       // tile 2I at kc (b0), 2I+1 at kc+64 (b1)
        GPHASE(0, 0, 0, sAm1(1, kc + 64);,  "")
        GPHASE(0, 1, 0, sBn1(1, kc + 64);,  "")
        GPHASE(1, 0, 0, sAm0(0, kc + 128);, "")
        GPHASE(1, 1, 0, sBn0(0, kc + 128);, "s_waitcnt vmcnt(4)")
        GPHASE(0, 0, 1, sAm1(0, kc + 128);, "")
        GPHASE(0, 1, 1, sBn1(0, kc + 128);, "")
        GPHASE(1, 0, 1, sAm0(1, kc + 192);, "")
        GPHASE(1, 1, 1, sBn0(1, kc + 192);, "s_waitcnt vmcnt(4)")
    }
    // peeled last iteration: finish b1 (tile nk-1) in ph1/ph2, drain at ph4
    {
        const int kc = (niter - 1) * 128;
        GPHASE(0, 0, 0, sAm1(1, kc + 64);, "")
        GPHASE(0, 1, 0, sBn1(1, kc + 64);, "")
        GPHASE(1, 0, 0, {};,               "")
        GPHASE(1, 1, 0, {};,               "s_waitcnt vmcnt(0)")
        GPHASE(0, 0, 1, {};,               "")
        GPHASE(0, 1, 1, {};,               "")
        GPHASE(1, 0, 1, {};,               "")
        GPHASE(1, 1, 1, {};,               "")
    }
#undef GPHASE

    // C-write: rows m0 + (w>>2)*128 + mi*16 + quad*4 + rg; cols n0 + (w&3)*64 + nj*16 + n16
    #pragma unroll
    for (int mi = 0; mi < 8; ++mi) {
        #pragma unroll
        for (int nj = 0; nj < 4; ++nj) {
            int rbase = m0 + (w >> 2) * 128 + mi * 16 + quad * 4;
            int col   = n0 + (w & 3) * 64 + nj * 16 + n16;
            #pragma unroll
            for (int rg = 0; rg < 4; ++rg)
                store_c(C + (size_t)(rbase + rg) * N + col, acc[mi][nj][rg]);
        }
    }
}

// ---------------------------------------------------------------------------
// RoPE: read bf16 Q/K from fused QKV [S][4096], write Qb/Kb (SCALE folded).
// ---------------------------------------------------------------------------
__global__ __launch_bounds__(256) void rope_kernel(const unsigned short* __restrict__ QKV,
                                                   unsigned short* __restrict__ Qb,
                                                   unsigned short* __restrict__ Kb,
                                                   const int* __restrict__ pos_ids)
{
    int id   = blockIdx.x * 256 + threadIdx.x;   // S * 12 * 128 threads
    int d    = id & 127;
    int rest = id >> 7;
    int hh   = rest % 12;
    int i    = rest / 12;
    float pos = (float)pos_ids[i];
    float inv = __expf((float)d * (-9.210340371976184f / 128.0f));   // 10000^(-d/128)
    float ang = pos * inv;
    float sn, cs;
    sincosf(ang, &sn, &cs);
    if (hh < HQ) {
        const unsigned short* p = QKV + (size_t)i * QKVDIM + hh * D + d;
        float x0 = bf2f(p[0]), x1 = bf2f(p[128]);
        unsigned short* q = Qb + (size_t)i * QDIM + hh * D + d;
        q[0]   = (unsigned short)f2bf((x0 * cs - x1 * sn) * SCALE);
        q[128] = (unsigned short)f2bf((x1 * cs + x0 * sn) * SCALE);
    } else {
        const unsigned short* p = QKV + (size_t)i * QKVDIM + QDIM + (hh - HQ) * D + d;
        float x0 = bf2f(p[0]), x1 = bf2f(p[128]);
        unsigned short* k = Kb + (size_t)i * KVDIM + (hh - HQ) * D + d;
        k[0]   = (unsigned short)f2bf(x0 * cs - x1 * sn);
        k[128] = (unsigned short)f2bf(x1 * cs + x0 * sn);
    }
}

// ---------------------------------------------------------------------------
// V transpose: fused QKV [S][4096] cols 3072..4095 -> Vt [KVDIM][S] bf16.
// ---------------------------------------------------------------------------
__global__ __launch_bounds__(256) void transpose_v(const unsigned short* __restrict__ QKV,
                                                   unsigned short* __restrict__ Vt)
{
    __shared__ float tile[64][65];
    const int s0 = blockIdx.x * 64, d0 = blockIdx.y * 64;
    const int t = threadIdx.x;
    #pragma unroll
    for (int it = 0; it < 4; ++it) {
        int flat = it * 256 + t;
        int r  = flat >> 4;
        int c4 = (flat & 15) * 4;
        uint2 v = *(const uint2*)(QKV + (size_t)(s0 + r) * QKVDIM + (QDIM + KVDIM) + d0 + c4);
        tile[r][c4 + 0] = bf2f(v.x & 0xffffu); tile[r][c4 + 1] = bf2f(v.x >> 16);
        tile[r][c4 + 2] = bf2f(v.y & 0xffffu); tile[r][c4 + 3] = bf2f(v.y >> 16);
    }
    __syncthreads();
    #pragma unroll
    for (int it = 0; it < 4; ++it) {
        int flat = it * 256 + t;
        int dr  = flat >> 4;
        int sc4 = (flat & 15) * 4;
        uint2 o;
        o.x = f2bf(tile[sc4 + 0][dr]) | (f2bf(tile[sc4 + 1][dr]) << 16);
        o.y = f2bf(tile[sc4 + 2][dr]) | (f2bf(tile[sc4 + 3][dr]) << 16);
        *(uint2*)(Vt + (size_t)(d0 + dr) * S + s0 + sc4) = o;
    }
}

// ---------------------------------------------------------------------------
// MFMA flash attention, FIXED-MAX softmax + SPLIT-KV load balancing.
// Fixed shift m=50 (valid since softcap bounds scores to [-50,50]) makes
// partial (O_raw, l) from disjoint jt-ranges combine by PLAIN ADDITION.
// Work: tiles(g) = 2g+2 (g<32) else 66. Split every (h, g>=16) jt-range
// into 2 halves (17..33 tiles); g<16 unsplit (2..32 tiles). Grid = 896,
// descending-work bid order (dynamic refill backfills), h = bid&7 keeps
// per-head XCD/L2 affinity. Split blocks write raw bf16 O-partials + f32
// row-sums to workspace; attn_combine reduces. Inner loop identical to R6.
// ---------------------------------------------------------------------------
__global__ __launch_bounds__(256, 2) void attn_kernel(const unsigned short* __restrict__ Qb,
                                                      const unsigned short* __restrict__ Kb,
                                                      const unsigned short* __restrict__ Vt,
                                                      unsigned short* __restrict__ O,
                                                      unsigned short* __restrict__ Op0,
                                                      unsigned short* __restrict__ Op1,
                                                      float* __restrict__ Lp0,
                                                      float* __restrict__ Lp1)
{
    __shared__ unsigned short Ks[2][32 * 256];
    __shared__ unsigned short Vs[2][256 * 32];
    __shared__ unsigned short Ps[4 * 512];
    const int t = threadIdx.x;
    const int bid = blockIdx.x;

    // bid -> (h, g, half, split), descending work within each class
    int h, g, half;
    bool split;
    if (bid < 768) {            // split halves: g = 63..16 (work 33..17)
        split = true;
        h = bid & 7;
        int rest = bid >> 3;    // 0..95
        half = rest & 1;
        g = 63 - (rest >> 1);   // 63..16
    } else {                    // unsplit: g = 15..0 (work 32..2)
        split = false;
        h = bid & 7;
        half = 0;
        g = 15 - ((bid - 768) >> 3);
    }
    const int kvh = h >> 1;
    const int i0 = g * 64;
    const int w = t >> 6, lid = t & 63, n16 = lid & 15, quad = lid >> 4;
    const int qbase = i0 + w * 16;
    unsigned short* Pw = Ps + w * 512;

    const int jlo = (i0 >= SW) ? ((i0 - (SW - 1)) >> 5) : 0;
    const int jhi = (i0 + 63) >> 5;
    int jt0 = jlo, jt1 = jhi;
    if (split) {
        int mid = (jlo + jhi + 1) >> 1;    // both halves nonempty for g>=16
        if (half == 0) jt1 = mid - 1; else jt0 = mid;
    }

    auto stage = [&](int buf, int j0) {
        #pragma unroll
        for (int it = 0; it < 4; ++it) {
            int f = it * 4 + w;
            int nt = f >> 3, ks = f & 7;
            glls16(Kb + (size_t)(j0 + nt * 16 + n16) * KVDIM + kvh * D + ks * 32 + quad * 8,
                   &Ks[buf][f * 512]);
        }
        #pragma unroll
        for (int it = 0; it < 4; ++it) {
            int f = it * 4 + w;
            glls16(Vt + (size_t)(kvh * D + f * 16 + n16) * S + j0 + quad * 8,
                   &Vs[buf][f * 512]);
        }
    };

    short8 qf[8];
    #pragma unroll
    for (int ks = 0; ks < 8; ++ks)
        qf[ks] = *(const short8*)(Qb + (size_t)(qbase + n16) * QDIM + h * D + ks * 32 + quad * 8);

    float lacc[4] = {0.f, 0.f, 0.f, 0.f};
    f32x4 Oacc[16] = {};

    stage(0, jt0 * 32);
    int cur = 0;

    for (int jt = jt0; jt <= jt1; ++jt) {
        const int j0 = jt * 32;
        asm volatile("s_waitcnt vmcnt(0)" ::: "memory");
        __syncthreads();
        if (jt < jt1) stage(cur ^ 1, (jt + 1) * 32);

        f32x4 sc[2] = {};
        __builtin_amdgcn_s_setprio(1);
        #pragma unroll
        for (int ks = 0; ks < 8; ++ks) {
            #pragma unroll
            for (int nt = 0; nt < 2; ++nt) {
                short8 kf = *(const short8*)(&Ks[cur][(nt * 8 + ks) * 512 + lid * 8]);
                sc[nt] = __builtin_amdgcn_mfma_f32_16x16x32_bf16(qf[ks], kf, sc[nt], 0, 0, 0);
            }
        }
        __builtin_amdgcn_s_setprio(0);

        #pragma unroll
        for (int nt = 0; nt < 2; ++nt) {
            int j = j0 + nt * 16 + n16;
            #pragma unroll
            for (int rg = 0; rg < 4; ++rg) {
                int iq = qbase + quad * 4 + rg;
                float e = __expf(sc[nt][rg] * (2.0f / SOFTCAP));
                float p = __expf(-100.0f * __builtin_amdgcn_rcpf(e + 1.0f));
                bool ok = (j <= iq) && (iq - j < SW);
                p = ok ? p : 0.0f;
                lacc[rg] += p;
                Pw[(quad * 4 + rg + 16 * (nt * 2 + (n16 >> 3))) * 8 + (n16 & 7)]
                    = (unsigned short)f2bf(p);
            }
        }

        asm volatile("s_waitcnt lgkmcnt(0)" ::: "memory");

        short8 pf = *(const short8*)(Pw + lid * 8);
        __builtin_amdgcn_s_setprio(1);
        #pragma unroll
        for (int dt = 0; dt < 16; ++dt) {
            short8 vf = *(const short8*)(&Vs[cur][dt * 512 + lid * 8]);
            Oacc[dt] = __builtin_amdgcn_mfma_f32_16x16x32_bf16(pf, vf, Oacc[dt], 0, 0, 0);
        }
        __builtin_amdgcn_s_setprio(0);
        cur ^= 1;
    }

    // row-sum reduce across the 16 key-lanes (uniform within each n16 group)
    float rsum[4];
    #pragma unroll
    for (int rg = 0; rg < 4; ++rg) {
        float rs = lacc[rg];
        rs += __shfl_xor(rs, 1); rs += __shfl_xor(rs, 2);
        rs += __shfl_xor(rs, 4); rs += __shfl_xor(rs, 8);
        rsum[rg] = rs;
    }

    if (!split) {
        #pragma unroll
        for (int dt = 0; dt < 16; ++dt) {
            int col = h * D + dt * 16 + n16;
            #pragma unroll
            for (int rg = 0; rg < 4; ++rg) {
                int row = qbase + quad * 4 + rg;
                O[(size_t)row * QDIM + col] = (unsigned short)f2bf(Oacc[dt][rg] / rsum[rg]);
            }
        }
    } else {
        unsigned short* Op = half ? Op1 : Op0;
        float* Lp = half ? Lp1 : Lp0;
        if (n16 == 0) {
            #pragma unroll
            for (int rg = 0; rg < 4; ++rg)
                Lp[(size_t)(qbase - 1024 + quad * 4 + rg) * 8 + h] = rsum[rg];
        }
        #pragma unroll
        for (int dt = 0; dt < 16; ++dt) {
            int col = h * D + dt * 16 + n16;
            #pragma unroll
            for (int rg = 0; rg < 4; ++rg) {
                int prow = qbase - 1024 + quad * 4 + rg;
                Op[(size_t)prow * QDIM + col] = (unsigned short)f2bf(Oacc[dt][rg]);
            }
        }
    }
}

// ---------------------------------------------------------------------------
// Combine split-KV partials: O[row+1024] = (O0+O1) / (l0+l1), bf16 out.
// 3072 rows x 2048 cols, 8 cols/thread.
// ---------------------------------------------------------------------------
__global__ __launch_bounds__(256) void attn_combine(const unsigned short* __restrict__ Op0,
                                                    const unsigned short* __restrict__ Op1,
                                                    const float* __restrict__ Lp0,
                                                    const float* __restrict__ Lp1,
                                                    unsigned short* __restrict__ O)
{
    int tid = blockIdx.x * 256 + threadIdx.x;   // 3072*256 threads
    int row = tid >> 8;                         // 0..3071
    int c8  = (tid & 255) * 8;                  // col base
    int h   = c8 >> 8;                          // col / 256
    float rinv = 1.0f / (Lp0[(size_t)row * 8 + h] + Lp1[(size_t)row * 8 + h]);
    uint4 a = *(const uint4*)(Op0 + (size_t)row * QDIM + c8);
    uint4 b = *(const uint4*)(Op1 + (size_t)row * QDIM + c8);
    auto comb = [&](unsigned ua, unsigned ub) {
        float x0 = (bf2f(ua & 0xffffu) + bf2f(ub & 0xffffu)) * rinv;
        float x1 = (bf2f(ua >> 16) + bf2f(ub >> 16)) * rinv;
        return f2bf(x0) | (f2bf(x1) << 16);
    };
    uint4 o;
    o.x = comb(a.x, b.x); o.y = comb(a.y, b.y);
    o.z = comb(a.z, b.z); o.w = comb(a.w, b.w);
    *(uint4*)(O + (size_t)(row + 1024) * QDIM + c8) = o;
}

extern "C" void kernel_launch(void* const* d_in, const int* in_sizes, int n_in,
                              void* d_out, int out_size, void* d_ws, size_t ws_size,
                              hipStream_t stream) {
    const float* hidden = (const float*)d_in[0];
    // d_in[1] = attention_mask: recomputed analytically, not read
    const float* Wq = (const float*)d_in[2];
    const float* Wk = (const float*)d_in[3];
    const float* Wv = (const float*)d_in[4];
    const float* Wo = (const float*)d_in[5];
    const int* pos = (const int*)d_in[6];
    float* out = (float*)d_out;

    // workspace layout (85 MiB total, aggressive aliasing):
    //  [0,18M)   Hb  [S][2304] bf16            -> dead after QKV GEMM; Qb [S][2048] aliases
    //  [18,37M)  Wqkv bf16 (19M)               -> dead after QKV GEMM; during attn: Op0(12.6M)+Lp0;
    //                                             after combine: Wo bf16 (9M) aliases
    //  [37,69M)  QKVf [S][4096] bf16 (32M)     -> dead after rope+transpose; Oa (16M) at 37M,
    //                                             Op1(12.6M)+Lp1 at 53M during attn
    //  [69,77M)  Kb  [S][1024] bf16 (8M)
    //  [77,85M)  Vt  [1024][S] bf16 (8M)
    char* ws = (char*)d_ws;
    unsigned short* Hb   = (unsigned short*)(ws);
    unsigned short* Qb   = (unsigned short*)(ws);
    unsigned short* Wqkv = (unsigned short*)(ws + (size_t)(18 << 20));
    unsigned short* QKVf = (unsigned short*)(ws + (size_t)(37 << 20));
    unsigned short* Oa   = (unsigned short*)(ws + (size_t)(37 << 20));
    unsigned short* Op0  = (unsigned short*)(ws + (size_t)(18 << 20));
    float*          Lp0  = (float*)(ws + (size_t)(18 << 20) + (size_t)(13 << 20));
    unsigned short* Op1  = (unsigned short*)(ws + (size_t)(53 << 20));
    float*          Lp1  = (float*)(ws + (size_t)(53 << 20) + (size_t)(13 << 20));
    unsigned short* Kb   = (unsigned short*)(ws + (size_t)(69 << 20));
    unsigned short* Vt   = (unsigned short*)(ws + (size_t)(77 << 20));

    cvt_bf16<<<(S * HID) / 1024, 256, 0, stream>>>(hidden, Hb);
    cvt_bf16<<<(QDIM * HID) / 1024, 256, 0, stream>>>(Wq, Wqkv);
    cvt_bf16<<<(KVDIM * HID) / 1024, 256, 0, stream>>>(Wk, Wqkv + (size_t)QDIM * HID);
    cvt_bf16<<<(KVDIM * HID) / 1024, 256, 0, stream>>>(Wv, Wqkv + (size_t)(QDIM + KVDIM) * HID);

    // fused QKV projection on the 256^2 8-phase kernel: grid 16x16 = 256 blocks
    bf16_gemm_8ph<<<256, 512, 0, stream>>>(Hb, Wqkv, QKVf, S, QKVDIM, HID);

    rope_kernel<<<(S * 12 * 128) / 256, 256, 0, stream>>>(QKVf, Qb, Kb, pos);
    transpose_v<<<dim3(S / 64, KVDIM / 64), 256, 0, stream>>>(QKVf, Vt);

    // split-KV attention (896 blocks) + partial combine
    attn_kernel<<<896, 256, 0, stream>>>(Qb, Kb, Vt, Oa, Op0, Op1, Lp0, Lp1);
    attn_combine<<<3072, 256, 0, stream>>>(Op0, Op1, Lp0, Lp1, Oa);

    cvt_bf16<<<(HID * QDIM) / 1024, 256, 0, stream>>>(Wo, Wqkv);
    bf16_gemm_bt<float><<<dim3(HID / 128, S / 128), 256, 0, stream>>>(Oa, Wqkv, out, S, HID, QDIM);
}